// Round 3
// 483.098 us; speedup vs baseline: 1.0255x; 1.0255x over previous
//
#include <hip/hip_runtime.h>
#include <math.h>

#define BLOCK 256
#define N_MOD 8
#define NEG_INF (-__builtin_inff())

// ext_vector types so __builtin_nontemporal_load accepts them
typedef float vfloat4 __attribute__((ext_vector_type(4)));
typedef int   vint4   __attribute__((ext_vector_type(4)));

// one step of a strict-'>' sequential top-2 scan (keeps lower index on ties),
// carrying the softmax weight alongside each value
__device__ __forceinline__ void top2_scan(float vj, float wj,
                                          float& t1, float& tw1,
                                          float& t2, float& tw2)
{
    bool g1 = vj > t1;
    bool g2 = vj > t2;
    float nb2 = g1 ? t1  : (g2 ? vj : t2);
    float nw2 = g1 ? tw1 : (g2 ? wj : tw2);
    t1  = g1 ? vj : t1;
    tw1 = g1 ? wj : tw1;
    t2  = nb2;
    tw2 = nw2;
}

// merge this lane's half-row top-2 with the neighbor lane's (lane ^ 1) and
// produce the final per-row output. hi_half == true means this lane holds
// elements 4..7 (the higher indices). Tie-breaking: lower element index wins,
// matching jax.lax.top_k.
__device__ __forceinline__ float merge_pair(bool hi_half,
                                            float a1, float aw1,
                                            float a2, float aw2)
{
    // default width = wavefront (64) on gfx950
    float p1  = __shfl_xor(a1, 1);
    float pw1 = __shfl_xor(aw1, 1);
    float p2  = __shfl_xor(a2, 1);
    float pw2 = __shfl_xor(aw2, 1);

    // l* = the half with LOWER element indices (0..3), h* = higher (4..7)
    float l1  = hi_half ? p1  : a1,  l2  = hi_half ? p2  : a2;
    float lw1 = hi_half ? pw1 : aw1, lw2 = hi_half ? pw2 : aw2;
    float h1  = hi_half ? a1  : p1,  h2  = hi_half ? a2  : p2;
    float hw1 = hi_half ? aw1 : pw1, hw2 = hi_half ? aw2 : pw2;

    bool hg = h1 > l1;                 // tie -> low half wins slot 1
    float t1  = hg ? h1  : l1;
    float tw1 = hg ? hw1 : lw1;

    // slot-2 candidates: hg ? (l1 vs h2, tie->l1) : (h1 vs l2, tie->l2)
    float c1  = hg ? l1  : h1,  c2  = hg ? h2  : l2;
    float cw1 = hg ? lw1 : hw1, cw2 = hg ? hw2 : lw2;
    bool sel  = hg ? (c1 >= c2) : (c1 > c2);
    float t2  = sel ? c1  : c2;
    float tw2 = sel ? cw1 : cw2;

    return t1 * tw1 + t2 * tw2 + 0.5f * (t1 + t2);
}

__global__ __launch_bounds__(BLOCK) void wta_kernel(
    const float* __restrict__ x,
    const int*   __restrict__ mask,
    const float* __restrict__ W,
    float*       __restrict__ out,
    int B)
{
    const int tid  = threadIdx.x;
    const int lane = tid & 63;
    // each wave owns 64 consecutive rows
    const size_t wave_row0 = (size_t)blockIdx.x * BLOCK + (size_t)(tid & ~63);

    // softmax(W): wave-uniform scalar math; hides under the global loads
    float sw[N_MOD];
    #pragma unroll
    for (int j = 0; j < N_MOD; ++j) sw[j] = W[j];
    float mx = sw[0];
    #pragma unroll
    for (int j = 1; j < N_MOD; ++j) mx = fmaxf(mx, sw[j]);
    float s = 0.0f;
    #pragma unroll
    for (int j = 0; j < N_MOD; ++j) { sw[j] = __expf(sw[j] - mx); s += sw[j]; }
    float inv = 1.0f / s;
    #pragma unroll
    for (int j = 0; j < N_MOD; ++j) sw[j] *= inv;

    if (wave_row0 + 64 <= (size_t)B) {
        // ---- fast path: per-instruction DENSE loads (lane i -> base + i*16B),
        // 100% sector utilization per instruction, no reliance on L2 merging
        // of nt-hinted half-sector requests.
        const vfloat4* xw = (const vfloat4*)(x + wave_row0 * N_MOD);
        const vint4*   mw = (const vint4*)(mask + wave_row0 * N_MOD);
        vfloat4 xA = __builtin_nontemporal_load(xw + lane);        // rows 0..31 of tile
        vfloat4 xB = __builtin_nontemporal_load(xw + 64 + lane);   // rows 32..63
        vint4   mA = __builtin_nontemporal_load(mw + lane);
        vint4   mB = __builtin_nontemporal_load(mw + 64 + lane);

        // lane pair (2r, 2r+1) holds row r: even lane = elems 0..3, odd = 4..7
        const bool hi_half = (lane & 1) != 0;
        float w0 = hi_half ? sw[4] : sw[0];
        float w1 = hi_half ? sw[5] : sw[1];
        float w2 = hi_half ? sw[6] : sw[2];
        float w3 = hi_half ? sw[7] : sw[3];

        float a1 = NEG_INF, a2 = NEG_INF, aw1 = 0.f, aw2 = 0.f;
        top2_scan(mA.x ? xA.x : NEG_INF, w0, a1, aw1, a2, aw2);
        top2_scan(mA.y ? xA.y : NEG_INF, w1, a1, aw1, a2, aw2);
        top2_scan(mA.z ? xA.z : NEG_INF, w2, a1, aw1, a2, aw2);
        top2_scan(mA.w ? xA.w : NEG_INF, w3, a1, aw1, a2, aw2);
        float resA = merge_pair(hi_half, a1, aw1, a2, aw2);

        float b1 = NEG_INF, b2 = NEG_INF, bw1 = 0.f, bw2 = 0.f;
        top2_scan(mB.x ? xB.x : NEG_INF, w0, b1, bw1, b2, bw2);
        top2_scan(mB.y ? xB.y : NEG_INF, w1, b1, bw1, b2, bw2);
        top2_scan(mB.z ? xB.z : NEG_INF, w2, b1, bw1, b2, bw2);
        top2_scan(mB.w ? xB.w : NEG_INF, w3, b1, bw1, b2, bw2);
        float resB = merge_pair(hi_half, b1, bw1, b2, bw2);

        // even lanes write the A-row result (rows 0..31), odd lanes the B-row
        // result (rows 32..63): 64 distinct consecutive rows, one dense 256B store
        size_t orow = wave_row0 + (size_t)((lane & 1) * 32 + (lane >> 1));
        __builtin_nontemporal_store(hi_half ? resB : resA, out + orow);
    } else {
        // ---- tail path (never taken when B % 256 == 0): one row per lane
        size_t b = wave_row0 + (size_t)lane;
        if (b >= (size_t)B) return;
        float t1 = NEG_INF, t2 = NEG_INF, tw1 = 0.f, tw2 = 0.f;
        #pragma unroll
        for (int j = 0; j < N_MOD; ++j) {
            float vj = mask[b * N_MOD + j] ? x[b * N_MOD + j] : NEG_INF;
            top2_scan(vj, sw[j], t1, tw1, t2, tw2);
        }
        out[b] = t1 * tw1 + t2 * tw2 + 0.5f * (t1 + t2);
    }
}

extern "C" void kernel_launch(void* const* d_in, const int* in_sizes, int n_in,
                              void* d_out, int out_size, void* d_ws, size_t ws_size,
                              hipStream_t stream) {
    const float* x    = (const float*)d_in[0];
    const int*   mask = (const int*)d_in[1];
    const float* W    = (const float*)d_in[2];
    float*       out  = (float*)d_out;

    int B = out_size;  // 8388608 rows, one output per row
    int grid = (B + BLOCK - 1) / BLOCK;
    wta_kernel<<<grid, BLOCK, 0, stream>>>(x, mask, W, out, B);
}